// Round 18
// baseline (399.449 us; speedup 1.0000x reference)
//
#include <hip/hip_runtime.h>
#include <hip/hip_fp16.h>
#include <math.h>

// ---------------------------------------------------------------------------
// Problem constants (from reference)
// ---------------------------------------------------------------------------
#define HIDDEN 64
#define HEADS 2
#define NCOLS 448          // GEMM logical cols: q(128) k(128) v(128) s(64)
#define KV_COLS 256        // fp16 halves: chunk-interleaved k/v (R11 layout)
#define KV_ROW_BYTES 512
#define N_GRAPHS 64
#define LN_EPS 1e-5f
// 0.125 (1/sqrt(64)) * log2(e): scores land in log2 domain -> exp2f directly
#define Q_SCALE 0.18033688011112042f

typedef _Float16 half8 __attribute__((ext_vector_type(8)));
typedef float    f32x4 __attribute__((ext_vector_type(4)));

// kvh element index for head h, dim d, mat(0=k,1=v): mat*128 + (d>>2)*8 + h*4 + (d&3)
// qh row: [0..63] = q_h0 (plain dim order, pre-scaled), [64..127] = q_h1

// ---------------------------------------------------------------------------
// Cast fp32 -> fp16, vectorized (n multiple of 4)
// ---------------------------------------------------------------------------
__global__ void cast_f2h_kernel(const float* __restrict__ in, _Float16* __restrict__ out, int n4)
{
    int i = blockIdx.x * 256 + threadIdx.x;
    if (i < n4) {
        float4 v = *(const float4*)&in[i * 4];
        __half2 a = __floats2half2_rn(v.x, v.y);
        __half2 b = __floats2half2_rn(v.z, v.w);
        uint2 pk;
        pk.x = *(unsigned int*)&a;
        pk.y = *(unsigned int*)&b;
        *(uint2*)&out[i * 4] = pk;
    }
}

// ---------------------------------------------------------------------------
// Single upfront pack for ALL 3 layers (transposed fp16 Bt + fp32 biases).
// Bt[c][k] = W[k][c], q block scaled by Q_SCALE.
// ---------------------------------------------------------------------------
__device__ __forceinline__ float pack_elem(
    int c, int k, int K,
    const float* Wq, const float* Wk, const float* Wv, const float* Ws)
{
    if      (c < 128) return Wq[k * 128 + c] * Q_SCALE;
    else if (c < 256) return Wk[k * 128 + (c - 128)];
    else if (c < 384) return Wv[k * 128 + (c - 256)];
    else              return Ws[k * 64  + (c - 384)];
}

__device__ __forceinline__ float pack_bias(
    int c, const float* bq, const float* bk, const float* bv, const float* bs)
{
    if      (c < 128) return bq[c] * Q_SCALE;
    else if (c < 256) return bk[c - 128];
    else if (c < 384) return bv[c - 256];
    else              return bs[c - 384];
}

#define L0_SZ (448 * 128)
#define L12_SZ (448 * 64)
#define PACK_TOTAL (L0_SZ + 2 * L12_SZ + 3 * NCOLS)

__global__ void pack3_kernel(
    const float* __restrict__ Wq0, const float* __restrict__ Wk0,
    const float* __restrict__ Wv0, const float* __restrict__ Ws0,
    const float* __restrict__ bq0, const float* __restrict__ bk0,
    const float* __restrict__ bv0, const float* __restrict__ bs0,
    const float* __restrict__ Wq1, const float* __restrict__ Wk1,
    const float* __restrict__ Wv1, const float* __restrict__ Ws1,
    const float* __restrict__ bq1, const float* __restrict__ bk1,
    const float* __restrict__ bv1, const float* __restrict__ bs1,
    const float* __restrict__ Wq2, const float* __restrict__ Wk2,
    const float* __restrict__ Wv2, const float* __restrict__ Ws2,
    const float* __restrict__ bq2, const float* __restrict__ bk2,
    const float* __restrict__ bv2, const float* __restrict__ bs2,
    _Float16* __restrict__ Bt0, _Float16* __restrict__ Bt1,
    _Float16* __restrict__ Bt2, float* __restrict__ bc)   // bc: [3][448]
{
    int idx = blockIdx.x * 256 + threadIdx.x;
    if (idx < L0_SZ) {
        int c = idx / 128, k = idx - c * 128;
        Bt0[idx] = (_Float16)pack_elem(c, k, 128, Wq0, Wk0, Wv0, Ws0);
    } else if (idx < L0_SZ + L12_SZ) {
        int i = idx - L0_SZ;
        int c = i / 64, k = i - c * 64;
        Bt1[i] = (_Float16)pack_elem(c, k, 64, Wq1, Wk1, Wv1, Ws1);
    } else if (idx < L0_SZ + 2 * L12_SZ) {
        int i = idx - L0_SZ - L12_SZ;
        int c = i / 64, k = i - c * 64;
        Bt2[i] = (_Float16)pack_elem(c, k, 64, Wq2, Wk2, Wv2, Ws2);
    } else if (idx < PACK_TOTAL) {
        int i = idx - L0_SZ - 2 * L12_SZ;   // 0..1343
        int l = i / NCOLS, c = i - l * NCOLS;
        float b;
        if      (l == 0) b = pack_bias(c, bq0, bk0, bv0, bs0);
        else if (l == 1) b = pack_bias(c, bq1, bk1, bv1, bs1);
        else             b = pack_bias(c, bq2, bk2, bv2, bs2);
        bc[l * NCOLS + c] = b;
    }
}

// ---------------------------------------------------------------------------
// MFMA GEMM body: one wave = 16 rows x NT*16 cols, fp32 accum.
// B-frags from XOR-swizzled LDS (byte ^ (row&7)<<4). A-frag: one 16B global
// load per lane per k-step. C/D: row=(lane>>4)*4+reg, col=lane&15.
// Split epilogue: q -> qh fp16, skip -> qsk fp32, k/v -> kvh fp16 interleaved.
// ---------------------------------------------------------------------------
template<int K, int NT>
__device__ __forceinline__ void gemm_body(
    const _Float16* __restrict__ Ah, const float* __restrict__ bias,
    _Float16* __restrict__ qh, float* __restrict__ qsk, __half* __restrict__ kvh,
    const _Float16* Bs, int M, int colBase, int chunkRow0, int tid)
{
    int lane = tid & 63;
    int w    = tid >> 6;              // 0..7
    int fr   = lane & 15;
    int g    = lane >> 4;
    int row0 = chunkRow0 + w * 16;
    int arow = row0 + fr;
    if (arow > M - 1) arow = M - 1;   // clamp (stores guarded)

    f32x4 acc[NT];
    #pragma unroll
    for (int c = 0; c < NT; ++c) acc[c] = (f32x4){0.f, 0.f, 0.f, 0.f};

    #pragma unroll
    for (int ks = 0; ks < K / 32; ++ks) {
        int k0 = ks * 32 + g * 8;
        half8 af = *(const half8*)&Ah[(size_t)arow * K + k0];
        #pragma unroll
        for (int c = 0; c < NT; ++c) {
            int rl   = c * 16 + fr;
            int byte = rl * (K * 2) + k0 * 2;
            int sw   = byte ^ ((rl & 7) << 4);
            half8 bf = *(const half8*)((const char*)Bs + sw);
            acc[c] = __builtin_amdgcn_mfma_f32_16x16x32_f16(af, bf, acc[c], 0, 0, 0);
        }
    }

    #pragma unroll
    for (int c = 0; c < NT; ++c) {
        int col = colBase + c * 16 + fr;
        float bs = bias[col];
        #pragma unroll
        for (int j = 0; j < 4; ++j) {
            int row = row0 + g * 4 + j;
            if (row >= M) continue;
            float o = acc[c][j] + bs;
            if (col < 128) {
                qh[(size_t)row * 128 + col] = (_Float16)o;
            } else if (col >= 384) {
                qsk[(size_t)row * 64 + (col - 384)] = o;
            } else {
                int cc  = col - 128;
                int mat = cc >> 7;          // 0=k, 1=v
                int hh  = (cc >> 6) & 1;
                int d   = cc & 63;
                int pos = mat * 128 + (d >> 2) * 8 + hh * 4 + (d & 3);
                kvh[(size_t)row * KV_COLS + pos] = __float2half_rn(o);
            }
        }
    }
}

// ---------------------------------------------------------------------------
// MFMA GEMM kernel: 512 threads = 8 waves, chunk = 128 rows.
// FOUR-way column split (112 cols each, NT=7, acc=28 VGPR): LDS 28KB (K=128),
// launch_bounds(512,6) -> ~3 blocks/CU, 24 waves/CU.
// ---------------------------------------------------------------------------
template<int K>
__global__ __launch_bounds__(512, 6) void gemm_mfma_kernel(
    const _Float16* __restrict__ Ah,   // [M][K]
    const _Float16* __restrict__ Bt,   // [448][K]
    const float* __restrict__ bias,    // [448]
    _Float16* __restrict__ qh, float* __restrict__ qsk,
    __half* __restrict__ kvh, int M)
{
    __shared__ _Float16 Bs[112 * K];   // 28KB (K=128) / 14KB (K=64)

    int tid     = threadIdx.x;
    int colblk  = blockIdx.x & 3;
    int chunk   = blockIdx.x >> 2;
    int colBase = colblk * 112;

    // stage B panel with swizzle: dest_byte = src_byte ^ ((row&7)<<4)
    int bytes = 112 * K * 2;
    const char* src = (const char*)Bt + (size_t)colBase * K * 2;
    for (int i = tid * 16; i < bytes; i += 512 * 16) {
        int rl = i / (K * 2);
        int sw = i ^ ((rl & 7) << 4);
        *(half8*)((char*)Bs + sw) = *(const half8*)(src + i);
    }
    __syncthreads();

    gemm_body<K, 7>(Ah, bias, qh, qsk, kvh, Bs, M, colBase, chunk * 128, tid);
}

// ---------------------------------------------------------------------------
// CSR build: histogram -> 3-kernel parallel scan -> scatter (byte offsets)
// ---------------------------------------------------------------------------
__global__ void hist_kernel(const int* __restrict__ dst, int* __restrict__ counts, int E)
{
    int i = blockIdx.x * 256 + threadIdx.x;
    if (i < E) atomicAdd(&counts[dst[i]], 1);
}

__global__ __launch_bounds__(256) void block_reduce_kernel(
    const int* __restrict__ counts, int* __restrict__ bsum, int N)
{
    __shared__ int s[256];
    int t = threadIdx.x;
    int i = blockIdx.x * 256 + t;
    s[t] = (i < N) ? counts[i] : 0;
    __syncthreads();
    #pragma unroll
    for (int o = 128; o; o >>= 1) {
        if (t < o) s[t] += s[t + o];
        __syncthreads();
    }
    if (t == 0) bsum[blockIdx.x] = s[0];
}

__global__ __launch_bounds__(256) void scan_partials_kernel(
    const int* __restrict__ bsum, int* __restrict__ boff, int nb, int* __restrict__ rowN)
{
    __shared__ int s[256];
    int t = threadIdx.x;
    int v = (t < nb) ? bsum[t] : 0;
    s[t] = v;
    __syncthreads();
    #pragma unroll
    for (int o = 1; o < 256; o <<= 1) {
        int x = (t >= o) ? s[t - o] : 0;
        __syncthreads();
        s[t] += x;
        __syncthreads();
    }
    if (t < nb) boff[t] = s[t] - v;     // exclusive
    if (t == nb - 1) rowN[0] = s[t];    // total = row_ptr[N]
}

__global__ __launch_bounds__(256) void block_scan_kernel(
    const int* __restrict__ counts, const int* __restrict__ boff,
    int* __restrict__ row_ptr, int* __restrict__ cursor, int N)
{
    __shared__ int s[256];
    int t = threadIdx.x;
    int i = blockIdx.x * 256 + t;
    int v = (i < N) ? counts[i] : 0;
    s[t] = v;
    __syncthreads();
    #pragma unroll
    for (int o = 1; o < 256; o <<= 1) {
        int x = (t >= o) ? s[t - o] : 0;
        __syncthreads();
        s[t] += x;
        __syncthreads();
    }
    if (i < N) {
        int excl = s[t] - v + boff[blockIdx.x];
        row_ptr[i] = excl;
        cursor[i]  = excl;
    }
}

// stores PRE-MULTIPLIED byte offsets into kvh (src * 512)
__global__ void scatter_kernel(const int* __restrict__ ei, int* __restrict__ cursor,
                               int* __restrict__ src_off, int E)
{
    int i = blockIdx.x * 256 + threadIdx.x;
    if (i < E) {
        int d = ei[E + i];                    // dst
        int pos = atomicAdd(&cursor[d], 1);
        src_off[pos] = ei[i] * KV_ROW_BYTES;  // src byte offset
    }
}

// ---------------------------------------------------------------------------
// DPP 16-lane sum (pure VALU)
// ---------------------------------------------------------------------------
__device__ __forceinline__ float dpp_sum16(float x)
{
    float t;
    t = __int_as_float(__builtin_amdgcn_mov_dpp(__float_as_int(x), 0xB1,  0xF, 0xF, true)); x += t; // xor 1
    t = __int_as_float(__builtin_amdgcn_mov_dpp(__float_as_int(x), 0x4E,  0xF, 0xF, true)); x += t; // xor 2
    t = __int_as_float(__builtin_amdgcn_mov_dpp(__float_as_int(x), 0x141, 0xF, 0xF, true)); x += t; // half-mirror
    t = __int_as_float(__builtin_amdgcn_mov_dpp(__float_as_int(x), 0x140, 0xF, 0xF, true)); x += t; // row-mirror
    return x;
}

// ---------------------------------------------------------------------------
// Edge flash-step: one edge's K/V (packed uint4) against q0/q1; updates
// online-softmax state (m,s,acc per head). exp2 domain.
// ---------------------------------------------------------------------------
__device__ __forceinline__ void edge_step(
    const uint4& kraw, const uint4& vraw,
    const float4& q0, const float4& q1,
    float& m0, float& s0, float4& a0,
    float& m1, float& s1, float4& a1)
{
    const __half2* kp = (const __half2*)&kraw;
    float2 ka = __half22float2(kp[0]), kb = __half22float2(kp[1]);
    float2 kc = __half22float2(kp[2]), kd = __half22float2(kp[3]);

    float p0 = fmaf(q0.w, kb.y, fmaf(q0.z, kb.x, fmaf(q0.y, ka.y, q0.x * ka.x)));
    float p1 = fmaf(q1.w, kd.y, fmaf(q1.z, kd.x, fmaf(q1.y, kc.y, q1.x * kc.x)));
    float sc0 = dpp_sum16(p0);   // log2-domain score
    float sc1 = dpp_sum16(p1);

    const __half2* vp = (const __half2*)&vraw;
    float2 va = __half22float2(vp[0]), vb = __half22float2(vp[1]);
    float2 vc = __half22float2(vp[2]), vd = __half22float2(vp[3]);

    float nm0 = fmaxf(m0, sc0);
    float f0  = exp2f(m0 - nm0);
    float w0  = exp2f(sc0 - nm0);
    s0 = fmaf(s0, f0, w0);
    a0.x = fmaf(a0.x, f0, w0 * va.x);
    a0.y = fmaf(a0.y, f0, w0 * va.y);
    a0.z = fmaf(a0.z, f0, w0 * vb.x);
    a0.w = fmaf(a0.w, f0, w0 * vb.y);
    m0 = nm0;

    float nm1 = fmaxf(m1, sc1);
    float f1  = exp2f(m1 - nm1);
    float w1  = exp2f(sc1 - nm1);
    s1 = fmaf(s1, f1, w1);
    a1.x = fmaf(a1.x, f1, w1 * vc.x);
    a1.y = fmaf(a1.y, f1, w1 * vc.y);
    a1.z = fmaf(a1.z, f1, w1 * vd.x);
    a1.w = fmaf(a1.w, f1, w1 * vd.y);
    m1 = nm1;
}

// ---------------------------------------------------------------------------
// Fused edge kernel (R16-proven, at its gather-byte floor): one wave per dst
// node, 4 edge-groups x 16 lanes. Direct src_off[e] loads. fp16 K/V gathers:
// 2 x uint4/lane/edge. 2x-unrolled pipeline with alternating A/B buffers.
// cvt+fma score path. Branchless exp2 softmax. Head-mean + skip + ReLU + LN.
// CONDITIONAL OUTPUT: layers 0/1 (do_ln=1) write ONLY hh (fp16, feeds next
// GEMM); layer 2 (do_ln=0) writes ONLY hout (fp32, feeds pool). Each layer's
// other buffer was never read -> pure write savings.
// ---------------------------------------------------------------------------
__global__ __launch_bounds__(256) void edge_conv_kernel(
    const _Float16* __restrict__ qh, const float* __restrict__ qsk,
    const __half* __restrict__ kvh,
    const int* __restrict__ row_ptr, const int* __restrict__ src_off,
    const float* __restrict__ gamma, const float* __restrict__ beta,
    float* __restrict__ hout, _Float16* __restrict__ hh, int N, int do_ln)
{
    int wave = threadIdx.x >> 6;
    int lane = threadIdx.x & 63;
    int g    = lane >> 4;        // edge-group 0..3
    int sub  = lane & 15;        // dim-chunk 0..15 (4 dims each)
    int node = blockIdx.x * 4 + wave;
    if (node >= N) return;

    // q fp16 -> fp32 registers once per node (8 cvt, amortized over degree)
    const __half* qrow = (const __half*)(qh + (size_t)node * 128);
    float4 q0, q1;
    {
        uint2 p0 = *(const uint2*)&qrow[sub * 4];
        uint2 p1 = *(const uint2*)&qrow[64 + sub * 4];
        const __half2* h0 = (const __half2*)&p0;
        const __half2* h1 = (const __half2*)&p1;
        float2 a = __half22float2(h0[0]), b = __half22float2(h0[1]);
        float2 c = __half22float2(h1[0]), d = __half22float2(h1[1]);
        q0 = make_float4(a.x, a.y, b.x, b.y);
        q1 = make_float4(c.x, c.y, d.x, d.y);
    }

    int e0 = row_ptr[node], e1 = row_ptr[node + 1];
    int deg = e1 - e0;

    float  m0 = -1e30f, m1 = -1e30f;
    float  s0 = 0.f, s1 = 0.f;
    float4 a0 = make_float4(0.f, 0.f, 0.f, 0.f);
    float4 a1 = make_float4(0.f, 0.f, 0.f, 0.f);

    const char* kvb = (const char*)kvh;
    int  e    = e0 + g;
    bool have = (e < e1);
    uint4 kA, vA, kB, vB;
    if (have) {
        const char* jb = kvb + (size_t)(unsigned)src_off[e];
        kA = *(const uint4*)(jb + sub * 16);
        vA = *(const uint4*)(jb + 256 + sub * 16);
    }

    // 2x-unrolled pipeline with alternating buffers (no register rotation)
    while (have) {
        int  eB    = e + 4;
        bool haveB = (eB < e1);
        if (haveB) {
            const char* jb = kvb + (size_t)(unsigned)src_off[eB];
            kB = *(const uint4*)(jb + sub * 16);
            vB = *(const uint4*)(jb + 256 + sub * 16);
        }
        edge_step(kA, vA, q0, q1, m0, s0, a0, m1, s1, a1);
        if (!haveB) break;

        int  eA    = eB + 4;
        bool haveA = (eA < e1);
        if (haveA) {
            const char* jb = kvb + (size_t)(unsigned)src_off[eA];
            kA = *(const uint4*)(jb + sub * 16);
            vA = *(const uint4*)(jb + 256 + sub * 16);
        }
        edge_step(kB, vB, q0, q1, m0, s0, a0, m1, s1, a1);

        e = eA; have = haveA;
    }

    // merge flash states across the 4 groups (xor 16, then 32)
    #pragma unroll
    for (int offm = 16; offm <= 32; offm <<= 1) {
        float mo0 = __shfl_xor(m0, offm);
        float so0 = __shfl_xor(s0, offm);
        float4 ao0;
        ao0.x = __shfl_xor(a0.x, offm); ao0.y = __shfl_xor(a0.y, offm);
        ao0.z = __shfl_xor(a0.z, offm); ao0.w = __shfl_xor(a0.w, offm);
        float nm = fmaxf(m0, mo0);
        float fa = exp2f(m0 - nm), fb = exp2f(mo0 - nm);
        s0 = s0 * fa + so0 * fb;
        a0.x = a0.x * fa + ao0.x * fb; a0.y = a0.y * fa + ao0.y * fb;
        a0.z = a0.z * fa + ao0.z * fb; a0.w = a0.w * fa + ao0.w * fb;
        m0 = nm;

        float mo1 = __shfl_xor(m1, offm);
        float so1 = __shfl_xor(s1, offm);
        float4 ao1;
        ao1.x = __shfl_xor(a1.x, offm); ao1.y = __shfl_xor(a1.y, offm);
        ao1.z = __shfl_xor(a1.z, offm); ao1.w = __shfl_xor(a1.w, offm);
        nm = fmaxf(m1, mo1);
        fa = exp2f(m1 - nm); fb = exp2f(mo1 - nm);
        s1 = s1 * fa + so1 * fb;
        a1.x = a1.x * fa + ao1.x * fb; a1.y = a1.y * fa + ao1.y * fb;
        a1.z = a1.z * fa + ao1.z * fb; a1.w = a1.w * fa + ao1.w * fb;
        m1 = nm;
    }

    float4 skip = *(const float4*)&qsk[(size_t)node * 64 + sub * 4];
    float4 o;
    if (deg > 0) {
        float r0 = 0.5f / s0, r1 = 0.5f / s1;
        o.x = a0.x * r0 + a1.x * r1 + skip.x;
        o.y = a0.y * r0 + a1.y * r1 + skip.y;
        o.z = a0.z * r0 + a1.z * r1 + skip.z;
        o.w = a0.w * r0 + a1.w * r1 + skip.w;
    } else {
        o = skip;
    }
    o.x = fmaxf(o.x, 0.f); o.y = fmaxf(o.y, 0.f);
    o.z = fmaxf(o.z, 0.f); o.w = fmaxf(o.w, 0.f);

    if (do_ln) {
        float mu = dpp_sum16(o.x + o.y + o.z + o.w) * (1.0f / 64.0f);
        float dx = o.x - mu, dy = o.y - mu, dz = o.z - mu, dw = o.w - mu;
        float var = dpp_sum16(dx * dx + dy * dy + dz * dz + dw * dw) * (1.0f / 64.0f);
        float rs = rsqrtf(var + LN_EPS);
        float4 gm = *(const float4*)&gamma[sub * 4];
        float4 bt = *(const float4*)&beta[sub * 4];
        o.x = dx * rs * gm.x + bt.x;
        o.y = dy * rs * gm.y + bt.y;
        o.z = dz * rs * gm.z + bt.z;
        o.w = dw * rs * gm.w + bt.w;
    }
    if (g == 0) {
        if (do_ln) {
            // layers 0/1: only next-layer GEMM input (fp16)
            __half2 h01 = __floats2half2_rn(o.x, o.y);
            __half2 h23 = __floats2half2_rn(o.z, o.w);
            uint2 pk;
            pk.x = *(unsigned int*)&h01;
            pk.y = *(unsigned int*)&h23;
            *(uint2*)&hh[(size_t)node * HIDDEN + sub * 4] = pk;
        } else {
            // layer 2: only pool input (fp32)
            *(float4*)&hout[(size_t)node * HIDDEN + sub * 4] = o;
        }
    }
}

// ---------------------------------------------------------------------------
// Pooling: batch sorted. One wave per 32 nodes (1563 waves, ~6/CU).
// ---------------------------------------------------------------------------
#define POOL_CHUNK 32
__global__ __launch_bounds__(64) void pool_kernel(const float* __restrict__ h,
                                                  const int* __restrict__ batch,
                                                  float* __restrict__ pooled,
                                                  float* __restrict__ cnt, int N)
{
    int lane = threadIdx.x;
    int start = blockIdx.x * POOL_CHUNK;
    if (start >= N) return;
    int end = min(start + POOL_CHUNK, N);
    int b0 = batch[start];
    int b1 = batch[end - 1];

    if (b0 == b1) {
        float acc = 0.f;
        #pragma unroll 4
        for (int i = start; i < end; ++i)
            acc += h[(size_t)i * HIDDEN + lane];
        atomicAdd(&pooled[b0 * HIDDEN + lane], acc);
        if (lane == 0) atomicAdd(&cnt[b0], (float)(end - start));
    } else {
        float acc = 0.f;
        int cur = b0, c = 0;
        for (int i = start; i < end; ++i) {
            int b = batch[i];
            if (b != cur) {
                atomicAdd(&pooled[cur * HIDDEN + lane], acc);
                if (lane == 0) atomicAdd(&cnt[cur], (float)c);
                acc = 0.f; c = 0; cur = b;
            }
            acc += h[(size_t)i * HIDDEN + lane];
            ++c;
        }
        atomicAdd(&pooled[cur * HIDDEN + lane], acc);
        if (lane == 0) atomicAdd(&cnt[cur], (float)c);
    }
}

__global__ void final_kernel(const float* __restrict__ pooled, const float* __restrict__ cnt,
                             const float* __restrict__ Wp, const float* __restrict__ bp,
                             float* __restrict__ out)
{
    int g = threadIdx.x;   // 64 graphs
    float c = fmaxf(cnt[g], 1.0f);
    float s = 0.f;
    for (int d = 0; d < HIDDEN; ++d) s += pooled[g * HIDDEN + d] * Wp[d];
    out[g] = s / c + bp[0];
}

// ---------------------------------------------------------------------------
// Host launcher
// ---------------------------------------------------------------------------
extern "C" void kernel_launch(void* const* d_in, const int* in_sizes, int n_in,
                              void* d_out, int out_size, void* d_ws, size_t ws_size,
                              hipStream_t stream)
{
    const float* x    = (const float*)d_in[0];
    const int*   ei   = (const int*)d_in[1];
    const int*   batch= (const int*)d_in[2];

    const float* Wl[3][4];  // Wq, Wk, Wv, Ws
    const float* bl[3][4];  // bq, bk, bv, bs
    for (int l = 0; l < 3; ++l) {
        int b = 3 + l * 8;
        Wl[l][0] = (const float*)d_in[b + 0]; bl[l][0] = (const float*)d_in[b + 1];
        Wl[l][1] = (const float*)d_in[b + 2]; bl[l][1] = (const float*)d_in[b + 3];
        Wl[l][2] = (const float*)d_in[b + 4]; bl[l][2] = (const float*)d_in[b + 5];
        Wl[l][3] = (const float*)d_in[b + 6]; bl[l][3] = (const float*)d_in[b + 7];
    }
    const float* g0    = (const float*)d_in[27];
    const float* beta0 = (const float*)d_in[28];
    const float* g1    = (const float*)d_in[29];
    const float* beta1 = (const float*)d_in[30];
    const float* Wp    = (const float*)d_in[31];
    const float* bp    = (const float*)d_in[32];

    const int N = in_sizes[0] / 128;   // 50000
    const int E = in_sizes[1] / 2;     // 800000

    // workspace carve (256B aligned)
    size_t off = 0;
    auto carve = [&](size_t bytes) -> char* {
        char* p = (char*)d_ws + off;
        off = (off + bytes + 255) & ~(size_t)255;
        return p;
    };
    _Float16*  qh     = (_Float16*)carve((size_t)N * 128 * 2);
    float*     qsk    = (float*)carve((size_t)N * 64 * 4);
    __half*    kvh    = (__half*)carve((size_t)N * KV_COLS * 2);
    float*     h      = (float*)carve((size_t)N * HIDDEN * 4);
    _Float16*  hh     = (_Float16*)carve((size_t)N * HIDDEN * 2);
    _Float16*  xh     = (_Float16*)carve((size_t)N * 128 * 2);
    _Float16*  Bt0    = (_Float16*)carve((size_t)L0_SZ * 2);
    _Float16*  Bt1    = (_Float16*)carve((size_t)L12_SZ * 2);
    _Float16*  Bt2    = (_Float16*)carve((size_t)L12_SZ * 2);
    float*     bc     = (float*)carve(3 * NCOLS * 4);
    int*       counts = (int*)carve((size_t)N * 4);
    int*       row_ptr= (int*)carve((size_t)(N + 1) * 4);
    int*       cursor = (int*)carve((size_t)N * 4);
    int*       src_off = (int*)carve((size_t)E * 4);
    int*       bsum   = (int*)carve(1024 * 4);
    int*       boff   = (int*)carve(1024 * 4);
    float*     pooled = (float*)carve((size_t)(N_GRAPHS * HIDDEN + N_GRAPHS) * 4);
    float*     cntf   = pooled + N_GRAPHS * HIDDEN;

    const int nb = (N + 255) / 256;    // 196 scan blocks

    // ---- CSR build (dst is layer-invariant) ----
    hipMemsetAsync(counts, 0, (size_t)N * 4, stream);
    hist_kernel<<<(E + 255) / 256, 256, 0, stream>>>(ei + E, counts, E);
    block_reduce_kernel<<<nb, 256, 0, stream>>>(counts, bsum, N);
    scan_partials_kernel<<<1, 256, 0, stream>>>(bsum, boff, nb, &row_ptr[N]);
    block_scan_kernel<<<nb, 256, 0, stream>>>(counts, boff, row_ptr, cursor, N);
    scatter_kernel<<<(E + 255) / 256, 256, 0, stream>>>(ei, cursor, src_off, E);

    // ---- upfront: pack all 3 layers + cast x ----
    pack3_kernel<<<(PACK_TOTAL + 255) / 256, 256, 0, stream>>>(
        Wl[0][0], Wl[0][1], Wl[0][2], Wl[0][3], bl[0][0], bl[0][1], bl[0][2], bl[0][3],
        Wl[1][0], Wl[1][1], Wl[1][2], Wl[1][3], bl[1][0], bl[1][1], bl[1][2], bl[1][3],
        Wl[2][0], Wl[2][1], Wl[2][2], Wl[2][3], bl[2][0], bl[2][1], bl[2][2], bl[2][3],
        Bt0, Bt1, Bt2, bc);
    {
        int n4 = (N * 128) / 4;
        cast_f2h_kernel<<<(n4 + 255) / 256, 256, 0, stream>>>(x, xh, n4);
    }

    const int gemm_grid = 4 * ((N + 127) / 128);   // 4 col-blocks x 391 row-chunks

    // ---- 3 TransformerConv layers ----
    for (int l = 0; l < 3; ++l) {
        if (l == 0)
            gemm_mfma_kernel<128><<<gemm_grid, 512, 0, stream>>>(
                xh, Bt0, bc, qh, qsk, kvh, N);
        else if (l == 1)
            gemm_mfma_kernel<64><<<gemm_grid, 512, 0, stream>>>(
                hh, Bt1, bc + NCOLS, qh, qsk, kvh, N);
        else
            gemm_mfma_kernel<64><<<gemm_grid, 512, 0, stream>>>(
                hh, Bt2, bc + 2 * NCOLS, qh, qsk, kvh, N);
        int do_ln = (l < 2) ? 1 : 0;
        const float* gg = (l == 0) ? g0 : g1;
        const float* bb = (l == 0) ? beta0 : beta1;
        edge_conv_kernel<<<(N + 3) / 4, 256, 0, stream>>>(
            qh, qsk, kvh, row_ptr, src_off, gg, bb, h, hh, N, do_ln);
    }

    // ---- global mean pool + head ----
    hipMemsetAsync(pooled, 0, (size_t)(N_GRAPHS * HIDDEN + N_GRAPHS) * 4, stream);
    pool_kernel<<<(N + POOL_CHUNK - 1) / POOL_CHUNK, 64, 0, stream>>>(h, batch, pooled, cntf, N);
    final_kernel<<<1, 64, 0, stream>>>(pooled, cntf, Wp, bp, (float*)d_out);
}

// Round 19
// 382.067 us; speedup vs baseline: 1.0455x; 1.0455x over previous
//
#include <hip/hip_runtime.h>
#include <hip/hip_fp16.h>
#include <math.h>

// ---------------------------------------------------------------------------
// Problem constants (from reference)
// ---------------------------------------------------------------------------
#define HIDDEN 64
#define HEADS 2
#define NCOLS 448          // GEMM logical cols: q(128) k(128) v(128) s(64)
#define KV_COLS 256        // fp16: PLAIN [k0|k1|v0|v1] (= GEMM col order)
#define KV_ROW_BYTES 512
#define N_GRAPHS 64
#define LN_EPS 1e-5f
// 0.125 (1/sqrt(64)) * log2(e): scores land in log2 domain -> exp2f directly
#define Q_SCALE 0.18033688011112042f

typedef _Float16 half8 __attribute__((ext_vector_type(8)));
typedef float    f32x4 __attribute__((ext_vector_type(4)));

// qh row: [0..63] = q_h0 (plain dim order, pre-scaled), [64..127] = q_h1

// ---------------------------------------------------------------------------
// Cast fp32 -> fp16, vectorized (n multiple of 4)
// ---------------------------------------------------------------------------
__global__ void cast_f2h_kernel(const float* __restrict__ in, _Float16* __restrict__ out, int n4)
{
    int i = blockIdx.x * 256 + threadIdx.x;
    if (i < n4) {
        float4 v = *(const float4*)&in[i * 4];
        __half2 a = __floats2half2_rn(v.x, v.y);
        __half2 b = __floats2half2_rn(v.z, v.w);
        uint2 pk;
        pk.x = *(unsigned int*)&a;
        pk.y = *(unsigned int*)&b;
        *(uint2*)&out[i * 4] = pk;
    }
}

// ---------------------------------------------------------------------------
// Single upfront pack for ALL 3 layers (transposed fp16 Bt + fp32 biases).
// Bt[c][k] = W[k][c], q block scaled by Q_SCALE.
// ---------------------------------------------------------------------------
__device__ __forceinline__ float pack_elem(
    int c, int k, int K,
    const float* Wq, const float* Wk, const float* Wv, const float* Ws)
{
    if      (c < 128) return Wq[k * 128 + c] * Q_SCALE;
    else if (c < 256) return Wk[k * 128 + (c - 128)];
    else if (c < 384) return Wv[k * 128 + (c - 256)];
    else              return Ws[k * 64  + (c - 384)];
}

__device__ __forceinline__ float pack_bias(
    int c, const float* bq, const float* bk, const float* bv, const float* bs)
{
    if      (c < 128) return bq[c] * Q_SCALE;
    else if (c < 256) return bk[c - 128];
    else if (c < 384) return bv[c - 256];
    else              return bs[c - 384];
}

#define L0_SZ (448 * 128)
#define L12_SZ (448 * 64)
#define PACK_TOTAL (L0_SZ + 2 * L12_SZ + 3 * NCOLS)

__global__ void pack3_kernel(
    const float* __restrict__ Wq0, const float* __restrict__ Wk0,
    const float* __restrict__ Wv0, const float* __restrict__ Ws0,
    const float* __restrict__ bq0, const float* __restrict__ bk0,
    const float* __restrict__ bv0, const float* __restrict__ bs0,
    const float* __restrict__ Wq1, const float* __restrict__ Wk1,
    const float* __restrict__ Wv1, const float* __restrict__ Ws1,
    const float* __restrict__ bq1, const float* __restrict__ bk1,
    const float* __restrict__ bv1, const float* __restrict__ bs1,
    const float* __restrict__ Wq2, const float* __restrict__ Wk2,
    const float* __restrict__ Wv2, const float* __restrict__ Ws2,
    const float* __restrict__ bq2, const float* __restrict__ bk2,
    const float* __restrict__ bv2, const float* __restrict__ bs2,
    _Float16* __restrict__ Bt0, _Float16* __restrict__ Bt1,
    _Float16* __restrict__ Bt2, float* __restrict__ bc)   // bc: [3][448]
{
    int idx = blockIdx.x * 256 + threadIdx.x;
    if (idx < L0_SZ) {
        int c = idx / 128, k = idx - c * 128;
        Bt0[idx] = (_Float16)pack_elem(c, k, 128, Wq0, Wk0, Wv0, Ws0);
    } else if (idx < L0_SZ + L12_SZ) {
        int i = idx - L0_SZ;
        int c = i / 64, k = i - c * 64;
        Bt1[i] = (_Float16)pack_elem(c, k, 64, Wq1, Wk1, Wv1, Ws1);
    } else if (idx < L0_SZ + 2 * L12_SZ) {
        int i = idx - L0_SZ - L12_SZ;
        int c = i / 64, k = i - c * 64;
        Bt2[i] = (_Float16)pack_elem(c, k, 64, Wq2, Wk2, Wv2, Ws2);
    } else if (idx < PACK_TOTAL) {
        int i = idx - L0_SZ - 2 * L12_SZ;   // 0..1343
        int l = i / NCOLS, c = i - l * NCOLS;
        float b;
        if      (l == 0) b = pack_bias(c, bq0, bk0, bv0, bs0);
        else if (l == 1) b = pack_bias(c, bq1, bk1, bv1, bs1);
        else             b = pack_bias(c, bq2, bk2, bv2, bs2);
        bc[l * NCOLS + c] = b;
    }
}

// ---------------------------------------------------------------------------
// MFMA GEMM body: one wave = 16 rows x NT*16 cols, fp32 accum.
// B-frags from XOR-swizzled LDS (byte ^ (row&7)<<4). A-frag: one 16B global
// load per lane per k-step. C/D: row=(lane>>4)*4+reg, col=lane&15.
// Split epilogue: q -> qh fp16, skip -> qsk fp32, k/v -> kvh fp16 PLAIN
// layout (kvh[row][col-128]) -> consecutive lanes write contiguous 2B runs,
// fully coalesced (vs the old interleaved 8B-stride scatter).
// ---------------------------------------------------------------------------
template<int K, int NT>
__device__ __forceinline__ void gemm_body(
    const _Float16* __restrict__ Ah, const float* __restrict__ bias,
    _Float16* __restrict__ qh, float* __restrict__ qsk, __half* __restrict__ kvh,
    const _Float16* Bs, int M, int colBase, int chunkRow0, int tid)
{
    int lane = tid & 63;
    int w    = tid >> 6;              // 0..7
    int fr   = lane & 15;
    int g    = lane >> 4;
    int row0 = chunkRow0 + w * 16;
    int arow = row0 + fr;
    if (arow > M - 1) arow = M - 1;   // clamp (stores guarded)

    f32x4 acc[NT];
    #pragma unroll
    for (int c = 0; c < NT; ++c) acc[c] = (f32x4){0.f, 0.f, 0.f, 0.f};

    #pragma unroll
    for (int ks = 0; ks < K / 32; ++ks) {
        int k0 = ks * 32 + g * 8;
        half8 af = *(const half8*)&Ah[(size_t)arow * K + k0];
        #pragma unroll
        for (int c = 0; c < NT; ++c) {
            int rl   = c * 16 + fr;
            int byte = rl * (K * 2) + k0 * 2;
            int sw   = byte ^ ((rl & 7) << 4);
            half8 bf = *(const half8*)((const char*)Bs + sw);
            acc[c] = __builtin_amdgcn_mfma_f32_16x16x32_f16(af, bf, acc[c], 0, 0, 0);
        }
    }

    #pragma unroll
    for (int c = 0; c < NT; ++c) {
        int col = colBase + c * 16 + fr;
        float bs = bias[col];
        #pragma unroll
        for (int j = 0; j < 4; ++j) {
            int row = row0 + g * 4 + j;
            if (row >= M) continue;
            float o = acc[c][j] + bs;
            if (col < 128) {
                qh[(size_t)row * 128 + col] = (_Float16)o;
            } else if (col >= 384) {
                qsk[(size_t)row * 64 + (col - 384)] = o;
            } else {
                kvh[(size_t)row * KV_COLS + (col - 128)] = __float2half_rn(o);
            }
        }
    }
}

// ---------------------------------------------------------------------------
// MFMA GEMM kernel: 512 threads = 8 waves, chunk = 128 rows.
// FOUR-way column split (112 cols each, NT=7, acc=28 VGPR): LDS 28KB (K=128),
// launch_bounds(512,6) -> ~3 blocks/CU, 24 waves/CU.
// ---------------------------------------------------------------------------
template<int K>
__global__ __launch_bounds__(512, 6) void gemm_mfma_kernel(
    const _Float16* __restrict__ Ah,   // [M][K]
    const _Float16* __restrict__ Bt,   // [448][K]
    const float* __restrict__ bias,    // [448]
    _Float16* __restrict__ qh, float* __restrict__ qsk,
    __half* __restrict__ kvh, int M)
{
    __shared__ _Float16 Bs[112 * K];   // 28KB (K=128) / 14KB (K=64)

    int tid     = threadIdx.x;
    int colblk  = blockIdx.x & 3;
    int chunk   = blockIdx.x >> 2;
    int colBase = colblk * 112;

    // stage B panel with swizzle: dest_byte = src_byte ^ ((row&7)<<4)
    int bytes = 112 * K * 2;
    const char* src = (const char*)Bt + (size_t)colBase * K * 2;
    for (int i = tid * 16; i < bytes; i += 512 * 16) {
        int rl = i / (K * 2);
        int sw = i ^ ((rl & 7) << 4);
        *(half8*)((char*)Bs + sw) = *(const half8*)(src + i);
    }
    __syncthreads();

    gemm_body<K, 7>(Ah, bias, qh, qsk, kvh, Bs, M, colBase, chunk * 128, tid);
}

// ---------------------------------------------------------------------------
// CSR build: histogram -> 3-kernel parallel scan -> scatter (byte offsets)
// ---------------------------------------------------------------------------
__global__ void hist_kernel(const int* __restrict__ dst, int* __restrict__ counts, int E)
{
    int i = blockIdx.x * 256 + threadIdx.x;
    if (i < E) atomicAdd(&counts[dst[i]], 1);
}

__global__ __launch_bounds__(256) void block_reduce_kernel(
    const int* __restrict__ counts, int* __restrict__ bsum, int N)
{
    __shared__ int s[256];
    int t = threadIdx.x;
    int i = blockIdx.x * 256 + t;
    s[t] = (i < N) ? counts[i] : 0;
    __syncthreads();
    #pragma unroll
    for (int o = 128; o; o >>= 1) {
        if (t < o) s[t] += s[t + o];
        __syncthreads();
    }
    if (t == 0) bsum[blockIdx.x] = s[0];
}

__global__ __launch_bounds__(256) void scan_partials_kernel(
    const int* __restrict__ bsum, int* __restrict__ boff, int nb, int* __restrict__ rowN)
{
    __shared__ int s[256];
    int t = threadIdx.x;
    int v = (t < nb) ? bsum[t] : 0;
    s[t] = v;
    __syncthreads();
    #pragma unroll
    for (int o = 1; o < 256; o <<= 1) {
        int x = (t >= o) ? s[t - o] : 0;
        __syncthreads();
        s[t] += x;
        __syncthreads();
    }
    if (t < nb) boff[t] = s[t] - v;     // exclusive
    if (t == nb - 1) rowN[0] = s[t];    // total = row_ptr[N]
}

__global__ __launch_bounds__(256) void block_scan_kernel(
    const int* __restrict__ counts, const int* __restrict__ boff,
    int* __restrict__ row_ptr, int* __restrict__ cursor, int N)
{
    __shared__ int s[256];
    int t = threadIdx.x;
    int i = blockIdx.x * 256 + t;
    int v = (i < N) ? counts[i] : 0;
    s[t] = v;
    __syncthreads();
    #pragma unroll
    for (int o = 1; o < 256; o <<= 1) {
        int x = (t >= o) ? s[t - o] : 0;
        __syncthreads();
        s[t] += x;
        __syncthreads();
    }
    if (i < N) {
        int excl = s[t] - v + boff[blockIdx.x];
        row_ptr[i] = excl;
        cursor[i]  = excl;
    }
}

// stores PRE-MULTIPLIED byte offsets into kvh (src * 512)
__global__ void scatter_kernel(const int* __restrict__ ei, int* __restrict__ cursor,
                               int* __restrict__ src_off, int E)
{
    int i = blockIdx.x * 256 + threadIdx.x;
    if (i < E) {
        int d = ei[E + i];                    // dst
        int pos = atomicAdd(&cursor[d], 1);
        src_off[pos] = ei[i] * KV_ROW_BYTES;  // src byte offset
    }
}

// ---------------------------------------------------------------------------
// DPP 16-lane sum (pure VALU)
// ---------------------------------------------------------------------------
__device__ __forceinline__ float dpp_sum16(float x)
{
    float t;
    t = __int_as_float(__builtin_amdgcn_mov_dpp(__float_as_int(x), 0xB1,  0xF, 0xF, true)); x += t; // xor 1
    t = __int_as_float(__builtin_amdgcn_mov_dpp(__float_as_int(x), 0x4E,  0xF, 0xF, true)); x += t; // xor 2
    t = __int_as_float(__builtin_amdgcn_mov_dpp(__float_as_int(x), 0x141, 0xF, 0xF, true)); x += t; // half-mirror
    t = __int_as_float(__builtin_amdgcn_mov_dpp(__float_as_int(x), 0x140, 0xF, 0xF, true)); x += t; // row-mirror
    return x;
}

// ---------------------------------------------------------------------------
// Edge flash-step: one edge's K/V (4x uint2: k0,k1,v0,v1 4-dim chunks)
// against q0/q1; updates online-softmax state. exp2 domain.
// ---------------------------------------------------------------------------
__device__ __forceinline__ void edge_step(
    const uint2& k0r, const uint2& k1r, const uint2& v0r, const uint2& v1r,
    const float4& q0, const float4& q1,
    float& m0, float& s0, float4& a0,
    float& m1, float& s1, float4& a1)
{
    const __half2* k0p = (const __half2*)&k0r;
    const __half2* k1p = (const __half2*)&k1r;
    float2 ka = __half22float2(k0p[0]), kb = __half22float2(k0p[1]);
    float2 kc = __half22float2(k1p[0]), kd = __half22float2(k1p[1]);

    float p0 = fmaf(q0.w, kb.y, fmaf(q0.z, kb.x, fmaf(q0.y, ka.y, q0.x * ka.x)));
    float p1 = fmaf(q1.w, kd.y, fmaf(q1.z, kd.x, fmaf(q1.y, kc.y, q1.x * kc.x)));
    float sc0 = dpp_sum16(p0);   // log2-domain score
    float sc1 = dpp_sum16(p1);

    const __half2* v0p = (const __half2*)&v0r;
    const __half2* v1p = (const __half2*)&v1r;
    float2 va = __half22float2(v0p[0]), vb = __half22float2(v0p[1]);
    float2 vc = __half22float2(v1p[0]), vd = __half22float2(v1p[1]);

    float nm0 = fmaxf(m0, sc0);
    float f0  = exp2f(m0 - nm0);
    float w0  = exp2f(sc0 - nm0);
    s0 = fmaf(s0, f0, w0);
    a0.x = fmaf(a0.x, f0, w0 * va.x);
    a0.y = fmaf(a0.y, f0, w0 * va.y);
    a0.z = fmaf(a0.z, f0, w0 * vb.x);
    a0.w = fmaf(a0.w, f0, w0 * vb.y);
    m0 = nm0;

    float nm1 = fmaxf(m1, sc1);
    float f1  = exp2f(m1 - nm1);
    float w1  = exp2f(sc1 - nm1);
    s1 = fmaf(s1, f1, w1);
    a1.x = fmaf(a1.x, f1, w1 * vc.x);
    a1.y = fmaf(a1.y, f1, w1 * vc.y);
    a1.z = fmaf(a1.z, f1, w1 * vd.x);
    a1.w = fmaf(a1.w, f1, w1 * vd.y);
    m1 = nm1;
}

// ---------------------------------------------------------------------------
// Fused edge kernel (at its gather-byte floor): one wave per dst node,
// 4 edge-groups x 16 lanes. Direct src_off[e] loads. fp16 K/V gathers from
// PLAIN [k0|k1|v0|v1] rows: 4 x uint2/lane/edge (same 512B/row coverage as
// the old 2 x uint4 — byte-bound, neutral). 2x-unrolled A/B pipeline.
// cvt+fma score path. Branchless exp2 softmax. Head-mean + skip + ReLU + LN.
// Conditional output: layers 0/1 write only hh (fp16); layer 2 only h (fp32).
// ---------------------------------------------------------------------------
__global__ __launch_bounds__(256) void edge_conv_kernel(
    const _Float16* __restrict__ qh, const float* __restrict__ qsk,
    const __half* __restrict__ kvh,
    const int* __restrict__ row_ptr, const int* __restrict__ src_off,
    const float* __restrict__ gamma, const float* __restrict__ beta,
    float* __restrict__ hout, _Float16* __restrict__ hh, int N, int do_ln)
{
    int wave = threadIdx.x >> 6;
    int lane = threadIdx.x & 63;
    int g    = lane >> 4;        // edge-group 0..3
    int sub  = lane & 15;        // dim-chunk 0..15 (4 dims each)
    int node = blockIdx.x * 4 + wave;
    if (node >= N) return;

    // q fp16 -> fp32 registers once per node (8 cvt, amortized over degree)
    const __half* qrow = (const __half*)(qh + (size_t)node * 128);
    float4 q0, q1;
    {
        uint2 p0 = *(const uint2*)&qrow[sub * 4];
        uint2 p1 = *(const uint2*)&qrow[64 + sub * 4];
        const __half2* h0 = (const __half2*)&p0;
        const __half2* h1 = (const __half2*)&p1;
        float2 a = __half22float2(h0[0]), b = __half22float2(h0[1]);
        float2 c = __half22float2(h1[0]), d = __half22float2(h1[1]);
        q0 = make_float4(a.x, a.y, b.x, b.y);
        q1 = make_float4(c.x, c.y, d.x, d.y);
    }

    int e0 = row_ptr[node], e1 = row_ptr[node + 1];
    int deg = e1 - e0;

    float  m0 = -1e30f, m1 = -1e30f;
    float  s0 = 0.f, s1 = 0.f;
    float4 a0 = make_float4(0.f, 0.f, 0.f, 0.f);
    float4 a1 = make_float4(0.f, 0.f, 0.f, 0.f);

    const char* kvb = (const char*)kvh;
    int  e    = e0 + g;
    bool have = (e < e1);
    uint2 k0A, k1A, v0A, v1A, k0B, k1B, v0B, v1B;
    if (have) {
        const char* jb = kvb + (size_t)(unsigned)src_off[e];
        k0A = *(const uint2*)(jb + sub * 8);
        k1A = *(const uint2*)(jb + 128 + sub * 8);
        v0A = *(const uint2*)(jb + 256 + sub * 8);
        v1A = *(const uint2*)(jb + 384 + sub * 8);
    }

    // 2x-unrolled pipeline with alternating buffers (no register rotation)
    while (have) {
        int  eB    = e + 4;
        bool haveB = (eB < e1);
        if (haveB) {
            const char* jb = kvb + (size_t)(unsigned)src_off[eB];
            k0B = *(const uint2*)(jb + sub * 8);
            k1B = *(const uint2*)(jb + 128 + sub * 8);
            v0B = *(const uint2*)(jb + 256 + sub * 8);
            v1B = *(const uint2*)(jb + 384 + sub * 8);
        }
        edge_step(k0A, k1A, v0A, v1A, q0, q1, m0, s0, a0, m1, s1, a1);
        if (!haveB) break;

        int  eA    = eB + 4;
        bool haveA = (eA < e1);
        if (haveA) {
            const char* jb = kvb + (size_t)(unsigned)src_off[eA];
            k0A = *(const uint2*)(jb + sub * 8);
            k1A = *(const uint2*)(jb + 128 + sub * 8);
            v0A = *(const uint2*)(jb + 256 + sub * 8);
            v1A = *(const uint2*)(jb + 384 + sub * 8);
        }
        edge_step(k0B, k1B, v0B, v1B, q0, q1, m0, s0, a0, m1, s1, a1);

        e = eA; have = haveA;
    }

    // merge flash states across the 4 groups (xor 16, then 32)
    #pragma unroll
    for (int offm = 16; offm <= 32; offm <<= 1) {
        float mo0 = __shfl_xor(m0, offm);
        float so0 = __shfl_xor(s0, offm);
        float4 ao0;
        ao0.x = __shfl_xor(a0.x, offm); ao0.y = __shfl_xor(a0.y, offm);
        ao0.z = __shfl_xor(a0.z, offm); ao0.w = __shfl_xor(a0.w, offm);
        float nm = fmaxf(m0, mo0);
        float fa = exp2f(m0 - nm), fb = exp2f(mo0 - nm);
        s0 = s0 * fa + so0 * fb;
        a0.x = a0.x * fa + ao0.x * fb; a0.y = a0.y * fa + ao0.y * fb;
        a0.z = a0.z * fa + ao0.z * fb; a0.w = a0.w * fa + ao0.w * fb;
        m0 = nm;

        float mo1 = __shfl_xor(m1, offm);
        float so1 = __shfl_xor(s1, offm);
        float4 ao1;
        ao1.x = __shfl_xor(a1.x, offm); ao1.y = __shfl_xor(a1.y, offm);
        ao1.z = __shfl_xor(a1.z, offm); ao1.w = __shfl_xor(a1.w, offm);
        nm = fmaxf(m1, mo1);
        fa = exp2f(m1 - nm); fb = exp2f(mo1 - nm);
        s1 = s1 * fa + so1 * fb;
        a1.x = a1.x * fa + ao1.x * fb; a1.y = a1.y * fa + ao1.y * fb;
        a1.z = a1.z * fa + ao1.z * fb; a1.w = a1.w * fa + ao1.w * fb;
        m1 = nm;
    }

    float4 skip = *(const float4*)&qsk[(size_t)node * 64 + sub * 4];
    float4 o;
    if (deg > 0) {
        float r0 = 0.5f / s0, r1 = 0.5f / s1;
        o.x = a0.x * r0 + a1.x * r1 + skip.x;
        o.y = a0.y * r0 + a1.y * r1 + skip.y;
        o.z = a0.z * r0 + a1.z * r1 + skip.z;
        o.w = a0.w * r0 + a1.w * r1 + skip.w;
    } else {
        o = skip;
    }
    o.x = fmaxf(o.x, 0.f); o.y = fmaxf(o.y, 0.f);
    o.z = fmaxf(o.z, 0.f); o.w = fmaxf(o.w, 0.f);

    if (do_ln) {
        float mu = dpp_sum16(o.x + o.y + o.z + o.w) * (1.0f / 64.0f);
        float dx = o.x - mu, dy = o.y - mu, dz = o.z - mu, dw = o.w - mu;
        float var = dpp_sum16(dx * dx + dy * dy + dz * dz + dw * dw) * (1.0f / 64.0f);
        float rs = rsqrtf(var + LN_EPS);
        float4 gm = *(const float4*)&gamma[sub * 4];
        float4 bt = *(const float4*)&beta[sub * 4];
        o.x = dx * rs * gm.x + bt.x;
        o.y = dy * rs * gm.y + bt.y;
        o.z = dz * rs * gm.z + bt.z;
        o.w = dw * rs * gm.w + bt.w;
    }
    if (g == 0) {
        if (do_ln) {
            // layers 0/1: only next-layer GEMM input (fp16)
            __half2 h01 = __floats2half2_rn(o.x, o.y);
            __half2 h23 = __floats2half2_rn(o.z, o.w);
            uint2 pk;
            pk.x = *(unsigned int*)&h01;
            pk.y = *(unsigned int*)&h23;
            *(uint2*)&hh[(size_t)node * HIDDEN + sub * 4] = pk;
        } else {
            // layer 2: only pool input (fp32)
            *(float4*)&hout[(size_t)node * HIDDEN + sub * 4] = o;
        }
    }
}

// ---------------------------------------------------------------------------
// Pooling: batch sorted. One wave per 32 nodes (1563 waves, ~6/CU).
// ---------------------------------------------------------------------------
#define POOL_CHUNK 32
__global__ __launch_bounds__(64) void pool_kernel(const float* __restrict__ h,
                                                  const int* __restrict__ batch,
                                                  float* __restrict__ pooled,
                                                  float* __restrict__ cnt, int N)
{
    int lane = threadIdx.x;
    int start = blockIdx.x * POOL_CHUNK;
    if (start >= N) return;
    int end = min(start + POOL_CHUNK, N);
    int b0 = batch[start];
    int b1 = batch[end - 1];

    if (b0 == b1) {
        float acc = 0.f;
        #pragma unroll 4
        for (int i = start; i < end; ++i)
            acc += h[(size_t)i * HIDDEN + lane];
        atomicAdd(&pooled[b0 * HIDDEN + lane], acc);
        if (lane == 0) atomicAdd(&cnt[b0], (float)(end - start));
    } else {
        float acc = 0.f;
        int cur = b0, c = 0;
        for (int i = start; i < end; ++i) {
            int b = batch[i];
            if (b != cur) {
                atomicAdd(&pooled[cur * HIDDEN + lane], acc);
                if (lane == 0) atomicAdd(&cnt[cur], (float)c);
                acc = 0.f; c = 0; cur = b;
            }
            acc += h[(size_t)i * HIDDEN + lane];
            ++c;
        }
        atomicAdd(&pooled[cur * HIDDEN + lane], acc);
        if (lane == 0) atomicAdd(&cnt[cur], (float)c);
    }
}

__global__ void final_kernel(const float* __restrict__ pooled, const float* __restrict__ cnt,
                             const float* __restrict__ Wp, const float* __restrict__ bp,
                             float* __restrict__ out)
{
    int g = threadIdx.x;   // 64 graphs
    float c = fmaxf(cnt[g], 1.0f);
    float s = 0.f;
    for (int d = 0; d < HIDDEN; ++d) s += pooled[g * HIDDEN + d] * Wp[d];
    out[g] = s / c + bp[0];
}

// ---------------------------------------------------------------------------
// Host launcher
// ---------------------------------------------------------------------------
extern "C" void kernel_launch(void* const* d_in, const int* in_sizes, int n_in,
                              void* d_out, int out_size, void* d_ws, size_t ws_size,
                              hipStream_t stream)
{
    const float* x    = (const float*)d_in[0];
    const int*   ei   = (const int*)d_in[1];
    const int*   batch= (const int*)d_in[2];

    const float* Wl[3][4];  // Wq, Wk, Wv, Ws
    const float* bl[3][4];  // bq, bk, bv, bs
    for (int l = 0; l < 3; ++l) {
        int b = 3 + l * 8;
        Wl[l][0] = (const float*)d_in[b + 0]; bl[l][0] = (const float*)d_in[b + 1];
        Wl[l][1] = (const float*)d_in[b + 2]; bl[l][1] = (const float*)d_in[b + 3];
        Wl[l][2] = (const float*)d_in[b + 4]; bl[l][2] = (const float*)d_in[b + 5];
        Wl[l][3] = (const float*)d_in[b + 6]; bl[l][3] = (const float*)d_in[b + 7];
    }
    const float* g0    = (const float*)d_in[27];
    const float* beta0 = (const float*)d_in[28];
    const float* g1    = (const float*)d_in[29];
    const float* beta1 = (const float*)d_in[30];
    const float* Wp    = (const float*)d_in[31];
    const float* bp    = (const float*)d_in[32];

    const int N = in_sizes[0] / 128;   // 50000
    const int E = in_sizes[1] / 2;     // 800000

    // workspace carve (256B aligned)
    size_t off = 0;
    auto carve = [&](size_t bytes) -> char* {
        char* p = (char*)d_ws + off;
        off = (off + bytes + 255) & ~(size_t)255;
        return p;
    };
    _Float16*  qh     = (_Float16*)carve((size_t)N * 128 * 2);
    float*     qsk    = (float*)carve((size_t)N * 64 * 4);
    __half*    kvh    = (__half*)carve((size_t)N * KV_COLS * 2);
    float*     h      = (float*)carve((size_t)N * HIDDEN * 4);
    _Float16*  hh     = (_Float16*)carve((size_t)N * HIDDEN * 2);
    _Float16*  xh     = (_Float16*)carve((size_t)N * 128 * 2);
    _Float16*  Bt0    = (_Float16*)carve((size_t)L0_SZ * 2);
    _Float16*  Bt1    = (_Float16*)carve((size_t)L12_SZ * 2);
    _Float16*  Bt2    = (_Float16*)carve((size_t)L12_SZ * 2);
    float*     bc     = (float*)carve(3 * NCOLS * 4);
    int*       counts = (int*)carve((size_t)N * 4);
    int*       row_ptr= (int*)carve((size_t)(N + 1) * 4);
    int*       cursor = (int*)carve((size_t)N * 4);
    int*       src_off = (int*)carve((size_t)E * 4);
    int*       bsum   = (int*)carve(1024 * 4);
    int*       boff   = (int*)carve(1024 * 4);
    float*     pooled = (float*)carve((size_t)(N_GRAPHS * HIDDEN + N_GRAPHS) * 4);
    float*     cntf   = pooled + N_GRAPHS * HIDDEN;

    const int nb = (N + 255) / 256;    // 196 scan blocks

    // ---- CSR build (dst is layer-invariant) ----
    hipMemsetAsync(counts, 0, (size_t)N * 4, stream);
    hist_kernel<<<(E + 255) / 256, 256, 0, stream>>>(ei + E, counts, E);
    block_reduce_kernel<<<nb, 256, 0, stream>>>(counts, bsum, N);
    scan_partials_kernel<<<1, 256, 0, stream>>>(bsum, boff, nb, &row_ptr[N]);
    block_scan_kernel<<<nb, 256, 0, stream>>>(counts, boff, row_ptr, cursor, N);
    scatter_kernel<<<(E + 255) / 256, 256, 0, stream>>>(ei, cursor, src_off, E);

    // ---- upfront: pack all 3 layers + cast x ----
    pack3_kernel<<<(PACK_TOTAL + 255) / 256, 256, 0, stream>>>(
        Wl[0][0], Wl[0][1], Wl[0][2], Wl[0][3], bl[0][0], bl[0][1], bl[0][2], bl[0][3],
        Wl[1][0], Wl[1][1], Wl[1][2], Wl[1][3], bl[1][0], bl[1][1], bl[1][2], bl[1][3],
        Wl[2][0], Wl[2][1], Wl[2][2], Wl[2][3], bl[2][0], bl[2][1], bl[2][2], bl[2][3],
        Bt0, Bt1, Bt2, bc);
    {
        int n4 = (N * 128) / 4;
        cast_f2h_kernel<<<(n4 + 255) / 256, 256, 0, stream>>>(x, xh, n4);
    }

    const int gemm_grid = 4 * ((N + 127) / 128);   // 4 col-blocks x 391 row-chunks

    // ---- 3 TransformerConv layers ----
    for (int l = 0; l < 3; ++l) {
        if (l == 0)
            gemm_mfma_kernel<128><<<gemm_grid, 512, 0, stream>>>(
                xh, Bt0, bc, qh, qsk, kvh, N);
        else if (l == 1)
            gemm_mfma_kernel<64><<<gemm_grid, 512, 0, stream>>>(
                hh, Bt1, bc + NCOLS, qh, qsk, kvh, N);
        else
            gemm_mfma_kernel<64><<<gemm_grid, 512, 0, stream>>>(
                hh, Bt2, bc + 2 * NCOLS, qh, qsk, kvh, N);
        int do_ln = (l < 2) ? 1 : 0;
        const float* gg = (l == 0) ? g0 : g1;
        const float* bb = (l == 0) ? beta0 : beta1;
        edge_conv_kernel<<<(N + 3) / 4, 256, 0, stream>>>(
            qh, qsk, kvh, row_ptr, src_off, gg, bb, h, hh, N, do_ln);
    }

    // ---- global mean pool + head ----
    hipMemsetAsync(pooled, 0, (size_t)(N_GRAPHS * HIDDEN + N_GRAPHS) * 4, stream);
    pool_kernel<<<(N + POOL_CHUNK - 1) / POOL_CHUNK, 64, 0, stream>>>(h, batch, pooled, cntf, N);
    final_kernel<<<1, 64, 0, stream>>>(pooled, cntf, Wp, bp, (float*)d_out);
}